// Round 25
// baseline (141.265 us; speedup 1.0000x reference)
//
#include <hip/hip_runtime.h>
#include <hip/hip_bf16.h>

// ---------------- problem constants ----------------
#define F_IN   256
#define DIM    128
#define NCLS   16
#define BSH    9           // bucket shift: 512 nodes per bucket
#define NBMAX  256         // max buckets (N<=131072)
#define CAP    10240       // per-bucket pairs capacity (expected ~8.2K, +22 sigma)
#define PCAP   18432       // per-bucket padded col region

typedef short bf16x8 __attribute__((ext_vector_type(8)));
typedef float f32x4  __attribute__((ext_vector_type(4)));
typedef float f32x2  __attribute__((ext_vector_type(2)));

__device__ __forceinline__ unsigned short f2bf(float f) {
    union { float f; unsigned u; } v; v.f = f;
    unsigned r = v.u + 0x7fffu + ((v.u >> 16) & 1u);   // RNE
    return (unsigned short)(r >> 16);
}
__device__ __forceinline__ float bflo(unsigned v) { return __uint_as_float(v << 16); }
__device__ __forceinline__ float bfhi(unsigned v) { return __uint_as_float(v & 0xffff0000u); }

// ---------------- fat kernel 1: part (blocks 0..nbPart-1) || init/W1-repack (rest) ----------------
// bucketCnt must be memset to 0 before launch; pairs slot = b*CAP + old count.
__global__ __launch_bounds__(1024) void part_init_kernel(
        const int* __restrict__ src, const int* __restrict__ dst,
        int* __restrict__ bucketCnt, int2* __restrict__ pairs, int E,
        const float* __restrict__ W1, unsigned short* __restrict__ W1f,
        unsigned* __restrict__ h1dummy, unsigned* __restrict__ h2dummy,
        float* __restrict__ dinv, int N, int nbPart) {
    int t = threadIdx.x;
    if (blockIdx.x >= nbPart) {
        // ---- init body: W1 repack + dummy rows ----
        int gb = blockIdx.x - nbPart;
        if (gb == 0) {
            if (t < 32) h1dummy[t] = 0;            // 128 B fp8 dummy row
            else if (t < 40) h2dummy[t - 32] = 0;  // 32 B bf16 dummy row
            else if (t == 40) dinv[N] = 0.f;       // dummy dinv -> pad edges = 0
        }
        int tg = gb * 1024 + t;
        if (tg < 8 * 32 * 16 * 8) {
            int j = tg & 7, c = (tg >> 3) & 15, g = (tg >> 7) & 31, f = tg >> 12;
            W1f[tg] = f2bf(W1[(g * 8 + j) * DIM + f * 16 + c]);
        }
        return;
    }
    // ---- part body ----
    __shared__ int hist[NBMAX];
    __shared__ int pos[NBMAX];
    int base = blockIdx.x * 8192;
    int s[8], d[8];
#pragma unroll
    for (int k = 0; k < 8; k++) {
        int i = base + k * 1024 + t;
        bool v = (i < E);
        s[k] = v ? src[i] : 0;
        d[k] = v ? dst[i] : -1;
    }
    if (t < NBMAX) hist[t] = 0;
    __syncthreads();
#pragma unroll
    for (int k = 0; k < 8; k++)
        if (d[k] >= 0) atomicAdd(&hist[d[k] >> BSH], 1);
    __syncthreads();
    if (t < NBMAX && hist[t]) pos[t] = t * CAP + atomicAdd(&bucketCnt[t], hist[t]);
    __syncthreads();
#pragma unroll
    for (int k = 0; k < 8; k++)
        if (d[k] >= 0) {
            int p = atomicAdd(&pos[d[k] >> BSH], 1);
            pairs[p] = make_int2(s[k], d[k]);
        }
}

// ---------------- fat kernel 2 (512 thr, 32KB LDS): csr || gemm1 ----------------
// csr: 1 node/thread, padded scan -> rowInfo/dinv, LDS-cursor scatter -> col.
// gemm: 8 waves x 16 rows; W1f staged in TWO 32KB phases -> 4+ blocks/CU.
__global__ __launch_bounds__(512) void csr_gemm_kernel(
        const int2* __restrict__ pairs, const int* __restrict__ bucketCnt,
        int* __restrict__ rowInfo, float* __restrict__ dinv, int* __restrict__ col,
        const float* __restrict__ X, const unsigned short* __restrict__ W1f,
        unsigned char* __restrict__ H1, int N, int nbCsr) {
    __shared__ int sh[8192];   // 32KB
    int t = threadIdx.x;

    if (blockIdx.x < nbCsr) {
        // ---- CSR body: 512 threads, one node each ----
        int* cnt  = sh;          // [512]
        int* part = sh + 512;    // [512]
        int b = blockIdx.x;
        int n0 = b << BSH;
        int nn = N - n0; if (nn > 512) nn = 512;
        int in0 = b * CAP;
        int inEnd = in0 + bucketCnt[b];
        int out0 = b * PCAP;

        cnt[t] = 0;
        __syncthreads();
        for (int p = in0 + t; p < inEnd; p += 512)
            atomicAdd(&cnt[pairs[p].y - n0], 1);
        __syncthreads();

        int c0 = cnt[t];
        int p0 = (c0 + 15) & ~15;          // pad to 16
        part[t] = p0;
        __syncthreads();
        for (int off = 1; off < 512; off <<= 1) {
            int u = (t >= off) ? part[t - off] : 0;
            __syncthreads();
            part[t] += u;
            __syncthreads();
        }
        int e0 = out0 + part[t] - p0;      // padded exclusive start for node t
        __syncthreads();
        if (t < nn) {
            rowInfo[n0 + t] = ((e0 >> 4) << 12) | (p0 >> 4);
            dinv[n0 + t] = rsqrtf((float)(c0 + 1));
        }
        cnt[t] = e0;                        // cursor
        __syncthreads();

        for (int p = in0 + t; p < inEnd; p += 512) {
            int2 e = pairs[p];
            int q = atomicAdd(&cnt[e.y - n0], 1);
            col[q] = e.x;
        }
        __syncthreads();
        if (t < nn) for (int q = c0; q < p0; q++) col[e0 + q] = N;   // dummy pad
    } else {
        // ---- GEMM body: 8 waves x 16 rows = 128 rows/block; two-phase W1f staging ----
        int gb = blockIdx.x - nbCsr;
        int wm = t >> 6, l = t & 63;
        int lr = l & 15, lg = l >> 4;
        int bm = gb * 128 + wm * 16;

        int r = bm + lr;
        r = (r < N) ? r : (N - 1);
        const float* xp = X + (size_t)r * F_IN + lg * 8;

        // issue all 16 X loads first; first barrier drains them under the staging copy
        float4 u[16];
#pragma unroll
        for (int s = 0; s < 8; s++) {
            u[2 * s + 0] = *(const float4*)(xp + s * 32);
            u[2 * s + 1] = *(const float4*)(xp + s * 32 + 4);
        }

        f32x4 acc[8];
#pragma unroll
        for (int f = 0; f < 8; f++) acc[f] = (f32x4){0.f, 0.f, 0.f, 0.f};

        uint4* wv = (uint4*)sh;
        const unsigned short* w1s = (const unsigned short*)sh;

#pragma unroll
        for (int h = 0; h < 2; h++) {
            if (h) __syncthreads();                 // all waves done reading phase-0 LDS
            const uint4* wg = (const uint4*)W1f + h * 2048;   // 32KB half (f = 4h..4h+3)
#pragma unroll
            for (int i = 0; i < 4; i++) wv[t + i * 512] = wg[t + i * 512];
            __syncthreads();
#pragma unroll
            for (int s = 0; s < 8; s++) {
                float4 u0 = u[2 * s + 0];
                float4 u1 = u[2 * s + 1];
                bf16x8 a;
                a[0] = (short)f2bf(u0.x); a[1] = (short)f2bf(u0.y);
                a[2] = (short)f2bf(u0.z); a[3] = (short)f2bf(u0.w);
                a[4] = (short)f2bf(u1.x); a[5] = (short)f2bf(u1.y);
                a[6] = (short)f2bf(u1.z); a[7] = (short)f2bf(u1.w);
#pragma unroll
                for (int f = 0; f < 4; f++) {
                    bf16x8 b = *(const bf16x8*)(w1s + ((((f * 32 + s * 4 + lg) * 16) + lr) << 3));
                    acc[h * 4 + f] = __builtin_amdgcn_mfma_f32_16x16x32_bf16(a, b, acc[h * 4 + f], 0, 0, 0);
                }
            }
        }
#pragma unroll
        for (int rr = 0; rr < 4; rr++) {
            int row = bm + lg * 4 + rr;
            if (row < N) {
                int w0 = __builtin_amdgcn_cvt_pk_fp8_f32(acc[0][rr], acc[1][rr], 0, false);
                w0 = __builtin_amdgcn_cvt_pk_fp8_f32(acc[2][rr], acc[3][rr], w0, true);
                int w1 = __builtin_amdgcn_cvt_pk_fp8_f32(acc[4][rr], acc[5][rr], 0, false);
                w1 = __builtin_amdgcn_cvt_pk_fp8_f32(acc[6][rr], acc[7][rr], w1, true);
                uint2 pk; pk.x = (unsigned)w0; pk.y = (unsigned)w1;
                *(uint2*)(H1 + ((size_t)row << 7) + lr * 8) = pk;
            }
        }
    }
}

// ---------------- agg1 fused: sum(dv_s * H1u[s]) -> *di + b1 -> relu -> @W2 -> *di -> H2(bf16) ----------------
__global__ __launch_bounds__(256, 8) void agg1_kernel(const unsigned char* __restrict__ H1,
                                                      const int* __restrict__ rowInfo,
                                                      const int* __restrict__ col,
                                                      const float* __restrict__ dinv,
                                                      const float* __restrict__ b1,
                                                      const float* __restrict__ W2,
                                                      unsigned short* __restrict__ H2, int N) {
    __shared__ f32x4 a_lds4[4][32];
    int tid = threadIdx.x;
    int wave = tid >> 6, lane = tid & 63;
    int d = blockIdx.x * 4 + wave;
    int half = lane >> 5;
    int li = lane & 31;
    unsigned kb4 = (unsigned)li * 4;

    float di = 0.f;
    if (d < N) {
        di = dinv[d];
        unsigned sg = *(const unsigned*)(H1 + (((unsigned)d << 7) | kb4));   // self row (unscaled)
        if (half) sg = 0u;
        f32x2 dsp = {di, di};
        f32x2 acc01 = __builtin_amdgcn_cvt_pk_f32_fp8((int)sg, false) * dsp;
        f32x2 acc23 = __builtin_amdgcn_cvt_pk_f32_fp8((int)sg, true) * dsp;

        int info = rowInfo[d];
        int jb = (info >> 12) << 4;
        int jend = jb + ((info & 0xFFF) << 4);
        for (int j0 = jb; j0 < jend; j0 += 64) {
            int cnt = jend - j0; if (cnt > 64) cnt = 64;   // multiple of 16
            int eidx = col[j0 + lane];
            if ((unsigned)eidx > (unsigned)N) eidx = N;    // clamp poison at bucket tails
            float dv = dinv[eidx];
            for (int kk = 0; kk < cnt; kk += 16) {         // 8 pair-gathers in flight
                int sA = __shfl(eidx, kk + 0 + half),  sB = __shfl(eidx, kk + 2 + half);
                int sC = __shfl(eidx, kk + 4 + half),  sD = __shfl(eidx, kk + 6 + half);
                int sE = __shfl(eidx, kk + 8 + half),  sF = __shfl(eidx, kk + 10 + half);
                int sG = __shfl(eidx, kk + 12 + half), sH = __shfl(eidx, kk + 14 + half);
                float vA = __shfl(dv, kk + 0 + half),  vB = __shfl(dv, kk + 2 + half);
                float vC = __shfl(dv, kk + 4 + half),  vD = __shfl(dv, kk + 6 + half);
                float vE = __shfl(dv, kk + 8 + half),  vF = __shfl(dv, kk + 10 + half);
                float vG = __shfl(dv, kk + 12 + half), vH = __shfl(dv, kk + 14 + half);
                unsigned gA = *(const unsigned*)(H1 + (((unsigned)sA << 7) | kb4));
                unsigned gB = *(const unsigned*)(H1 + (((unsigned)sB << 7) | kb4));
                unsigned gC = *(const unsigned*)(H1 + (((unsigned)sC << 7) | kb4));
                unsigned gD = *(const unsigned*)(H1 + (((unsigned)sD << 7) | kb4));
                unsigned gE = *(const unsigned*)(H1 + (((unsigned)sE << 7) | kb4));
                unsigned gF = *(const unsigned*)(H1 + (((unsigned)sF << 7) | kb4));
                unsigned gG = *(const unsigned*)(H1 + (((unsigned)sG << 7) | kb4));
                unsigned gH = *(const unsigned*)(H1 + (((unsigned)sH << 7) | kb4));
                f32x2 wA = {vA, vA}, wB = {vB, vB}, wC = {vC, vC}, wD = {vD, vD};
                f32x2 wE = {vE, vE}, wF = {vF, vF}, wG = {vG, vG}, wH = {vH, vH};
                acc01 += __builtin_amdgcn_cvt_pk_f32_fp8((int)gA, false) * wA;
                acc23 += __builtin_amdgcn_cvt_pk_f32_fp8((int)gA, true)  * wA;
                acc01 += __builtin_amdgcn_cvt_pk_f32_fp8((int)gB, false) * wB;
                acc23 += __builtin_amdgcn_cvt_pk_f32_fp8((int)gB, true)  * wB;
                acc01 += __builtin_amdgcn_cvt_pk_f32_fp8((int)gC, false) * wC;
                acc23 += __builtin_amdgcn_cvt_pk_f32_fp8((int)gC, true)  * wC;
                acc01 += __builtin_amdgcn_cvt_pk_f32_fp8((int)gD, false) * wD;
                acc23 += __builtin_amdgcn_cvt_pk_f32_fp8((int)gD, true)  * wD;
                acc01 += __builtin_amdgcn_cvt_pk_f32_fp8((int)gE, false) * wE;
                acc23 += __builtin_amdgcn_cvt_pk_f32_fp8((int)gE, true)  * wE;
                acc01 += __builtin_amdgcn_cvt_pk_f32_fp8((int)gF, false) * wF;
                acc23 += __builtin_amdgcn_cvt_pk_f32_fp8((int)gF, true)  * wF;
                acc01 += __builtin_amdgcn_cvt_pk_f32_fp8((int)gG, false) * wG;
                acc23 += __builtin_amdgcn_cvt_pk_f32_fp8((int)gG, true)  * wG;
                acc01 += __builtin_amdgcn_cvt_pk_f32_fp8((int)gH, false) * wH;
                acc23 += __builtin_amdgcn_cvt_pk_f32_fp8((int)gH, true)  * wH;
            }
        }
        acc01.x += __shfl_xor(acc01.x, 32);
        acc01.y += __shfl_xor(acc01.y, 32);
        acc23.x += __shfl_xor(acc23.x, 32);
        acc23.y += __shfl_xor(acc23.y, 32);
        if (half == 0) {
            int p0 = li * 4;
            int f0 = ((p0 & 7) << 4) | (p0 >> 3);
            int f1 = (((p0 + 1) & 7) << 4) | ((p0 + 1) >> 3);
            int f2 = (((p0 + 2) & 7) << 4) | ((p0 + 2) >> 3);
            int f3 = (((p0 + 3) & 7) << 4) | ((p0 + 3) >> 3);
            f32x4 a;
            a[0] = fmaxf(fmaf(acc01.x, di, b1[f0]), 0.f);
            a[1] = fmaxf(fmaf(acc01.y, di, b1[f1]), 0.f);
            a[2] = fmaxf(fmaf(acc23.x, di, b1[f2]), 0.f);
            a[3] = fmaxf(fmaf(acc23.y, di, b1[f3]), 0.f);
            a_lds4[wave][li] = a;
        }
    }
    __syncthreads();
    if (d < N) {
        int c = lane & 15, kg = lane >> 4;
        const float* a_ldsf = (const float*)a_lds4[wave];
        const float* w2b = W2 + kg * 64 + c;
        float p = 0.f;
#pragma unroll
        for (int i = 0; i < 32; i++) {
            int w2off = ((i & 7) << 8) + ((i >> 3) << 4);
            p = fmaf(a_ldsf[kg * 32 + i], w2b[w2off], p);
        }
        p += __shfl_xor(p, 16);
        p += __shfl_xor(p, 32);
        if (lane < 16) H2[(size_t)d * NCLS + c] = f2bf(p * di);
    }
}

// ---------------- agg2 + log_softmax: 8 lanes/node, 2 classes/lane, 16-padded lists ----------------
__global__ __launch_bounds__(256, 8) void agg2_kernel(const unsigned short* __restrict__ H2,
                                                      const int* __restrict__ rowInfo,
                                                      const int* __restrict__ col,
                                                      const float* __restrict__ dinv,
                                                      const float* __restrict__ b2,
                                                      float* __restrict__ OUT, int N) {
    int tid = threadIdx.x;
    int g = tid >> 3, q = tid & 7;
    int d = blockIdx.x * 32 + g;
    if (d >= N) return;
    unsigned cb = (unsigned)q * 4;
    const char* H2b = (const char*)H2;
    float di = dinv[d];
    unsigned u = *(const unsigned*)(H2b + (((unsigned)d << 5) | cb));
    f32x2 acc; acc.x = bflo(u); acc.y = bfhi(u);
    int info = rowInfo[d];
    int jb = (info >> 12) << 4;
    int jend = jb + ((info & 0xFFF) << 4);
    for (int j = jb; j < jend; j += 8) {
        unsigned u0 = *(const unsigned*)(H2b + (((unsigned)col[j + 0] << 5) | cb));
        unsigned u1 = *(const unsigned*)(H2b + (((unsigned)col[j + 1] << 5) | cb));
        unsigned u2 = *(const unsigned*)(H2b + (((unsigned)col[j + 2] << 5) | cb));
        unsigned u3 = *(const unsigned*)(H2b + (((unsigned)col[j + 3] << 5) | cb));
        unsigned u4 = *(const unsigned*)(H2b + (((unsigned)col[j + 4] << 5) | cb));
        unsigned u5 = *(const unsigned*)(H2b + (((unsigned)col[j + 5] << 5) | cb));
        unsigned u6 = *(const unsigned*)(H2b + (((unsigned)col[j + 6] << 5) | cb));
        unsigned u7 = *(const unsigned*)(H2b + (((unsigned)col[j + 7] << 5) | cb));
        f32x2 v0; v0.x = bflo(u0); v0.y = bfhi(u0);
        f32x2 v1; v1.x = bflo(u1); v1.y = bfhi(u1);
        f32x2 v2; v2.x = bflo(u2); v2.y = bfhi(u2);
        f32x2 v3; v3.x = bflo(u3); v3.y = bfhi(u3);
        f32x2 v4; v4.x = bflo(u4); v4.y = bfhi(u4);
        f32x2 v5; v5.x = bflo(u5); v5.y = bfhi(u5);
        f32x2 v6; v6.x = bflo(u6); v6.y = bfhi(u6);
        f32x2 v7; v7.x = bflo(u7); v7.y = bfhi(u7);
        acc += ((v0 + v1) + (v2 + v3)) + ((v4 + v5) + (v6 + v7));
    }
    float l0 = fmaf(acc.x, di, b2[q * 2]);
    float l1 = fmaf(acc.y, di, b2[q * 2 + 1]);
    float m = fmaxf(l0, l1);
    m = fmaxf(m, __shfl_xor(m, 1, 8));
    m = fmaxf(m, __shfl_xor(m, 2, 8));
    m = fmaxf(m, __shfl_xor(m, 4, 8));
    float e = __expf(l0 - m) + __expf(l1 - m);
    e += __shfl_xor(e, 1, 8);
    e += __shfl_xor(e, 2, 8);
    e += __shfl_xor(e, 4, 8);
    float ls = __logf(e);
    float2 o; o.x = l0 - m - ls; o.y = l1 - m - ls;
    *(float2*)(OUT + ((size_t)d << 4) + q * 2) = o;
}

// ---------------- launch ----------------
extern "C" void kernel_launch(void* const* d_in, const int* in_sizes, int n_in,
                              void* d_out, int out_size, void* d_ws, size_t ws_size,
                              hipStream_t stream) {
    const float* x  = (const float*)d_in[0];
    const int*   ei = (const int*)d_in[1];
    const float* W1 = (const float*)d_in[2];
    const float* b1 = (const float*)d_in[3];
    const float* W2 = (const float*)d_in[4];
    const float* b2 = (const float*)d_in[5];
    float* out = (float*)d_out;

    const int N = in_sizes[0] / F_IN;    // 100000
    const int E = in_sizes[1] / 2;       // 1600000
    const int* src = ei;
    const int* dst = ei + E;
    const int nb = (N + (1 << BSH) - 1) >> BSH;   // 196 buckets

    // workspace layout (256B aligned)
    char* ws = (char*)d_ws;
    size_t off = 0;
    auto alloc = [&](size_t bytes) {
        size_t o = off;
        off += (bytes + 255) & ~(size_t)255;
        return (void*)(ws + o);
    };
    int*            bucketCnt   = (int*)alloc(NBMAX * 4);
    int*            rowInfo     = (int*)alloc((size_t)N * 4);
    float*          dinv        = (float*)alloc((size_t)(N + 1) * 4);
    int*            colw        = (int*)alloc((size_t)NBMAX * PCAP * 4);
    unsigned short* w1f         = (unsigned short*)alloc(32768 * 2);
    unsigned short* h2          = (unsigned short*)alloc((size_t)(N + 1) * NCLS * 2);
    // pairs and h1 must NOT overlap (csr reads pairs while gemm writes h1 in same kernel)
    int2*           pairs       = (int2*)alloc((size_t)NBMAX * CAP * 8);
    unsigned char*  h1          = (unsigned char*)alloc((size_t)(N + 1) * DIM);
    (void)ws_size;

    const int gridE = (E + 8191) / 8192;   // 196 part blocks
    const int initB = 32;                  // 32768 repack elems / 1024

    hipMemsetAsync(bucketCnt, 0, NBMAX * 4, stream);
    part_init_kernel<<<gridE + initB, 1024, 0, stream>>>(src, dst, bucketCnt, pairs, E,
                                                         W1, w1f,
                                                         (unsigned*)(h1 + (size_t)N * DIM),
                                                         (unsigned*)(h2 + (size_t)N * NCLS),
                                                         dinv, N, gridE);
    csr_gemm_kernel<<<nb + (N + 127) / 128, 512, 0, stream>>>(pairs, bucketCnt, rowInfo, dinv, colw,
                                                              x, w1f, h1, N, nb);
    agg1_kernel<<<(N + 3) / 4, 256, 0, stream>>>(h1, rowInfo, colw, dinv, b1, W2, h2, N);
    agg2_kernel<<<(N + 31) / 32, 256, 0, stream>>>(h2, rowInfo, colw, dinv, b2, out, N);
}

// Round 26
// 137.463 us; speedup vs baseline: 1.0277x; 1.0277x over previous
//
#include <hip/hip_runtime.h>
#include <hip/hip_bf16.h>

// ---------------- problem constants ----------------
#define F_IN   256
#define DIM    128
#define NCLS   16
#define BSH    9           // bucket shift: 512 nodes per bucket
#define NBMAX  256         // max buckets (N<=131072)
#define CAP    10240       // per-bucket pairs capacity (expected ~8.2K, +22 sigma)
#define PCAP   18432       // per-bucket padded col region

typedef short bf16x8 __attribute__((ext_vector_type(8)));
typedef float f32x4  __attribute__((ext_vector_type(4)));
typedef float f32x2  __attribute__((ext_vector_type(2)));

__device__ __forceinline__ unsigned short f2bf(float f) {
    union { float f; unsigned u; } v; v.f = f;
    unsigned r = v.u + 0x7fffu + ((v.u >> 16) & 1u);   // RNE
    return (unsigned short)(r >> 16);
}
__device__ __forceinline__ float bflo(unsigned v) { return __uint_as_float(v << 16); }
__device__ __forceinline__ float bfhi(unsigned v) { return __uint_as_float(v & 0xffff0000u); }

// ---------------- fat kernel 1: part (blocks 0..nbPart-1) || init/W1-repack (rest) ----------------
// bucketCnt must be memset to 0 before launch; pairs slot = b*CAP + old count.
__global__ __launch_bounds__(1024) void part_init_kernel(
        const int* __restrict__ src, const int* __restrict__ dst,
        int* __restrict__ bucketCnt, int2* __restrict__ pairs, int E,
        const float* __restrict__ W1, unsigned short* __restrict__ W1f,
        unsigned* __restrict__ h1dummy, unsigned* __restrict__ h2dummy,
        float* __restrict__ dinv, int N, int nbPart) {
    int t = threadIdx.x;
    if (blockIdx.x >= nbPart) {
        // ---- init body: W1 repack + dummy rows ----
        int gb = blockIdx.x - nbPart;
        if (gb == 0) {
            if (t < 32) h1dummy[t] = 0;            // 128 B fp8 dummy row
            else if (t < 40) h2dummy[t - 32] = 0;  // 32 B bf16 dummy row
            else if (t == 40) dinv[N] = 0.f;       // dummy dinv -> pad edges = 0
        }
        int tg = gb * 1024 + t;
        if (tg < 8 * 32 * 16 * 8) {
            int j = tg & 7, c = (tg >> 3) & 15, g = (tg >> 7) & 31, f = tg >> 12;
            W1f[tg] = f2bf(W1[(g * 8 + j) * DIM + f * 16 + c]);
        }
        return;
    }
    // ---- part body ----
    __shared__ int hist[NBMAX];
    __shared__ int pos[NBMAX];
    int base = blockIdx.x * 8192;
    int s[8], d[8];
#pragma unroll
    for (int k = 0; k < 8; k++) {
        int i = base + k * 1024 + t;
        bool v = (i < E);
        s[k] = v ? src[i] : 0;
        d[k] = v ? dst[i] : -1;
    }
    if (t < NBMAX) hist[t] = 0;
    __syncthreads();
#pragma unroll
    for (int k = 0; k < 8; k++)
        if (d[k] >= 0) atomicAdd(&hist[d[k] >> BSH], 1);
    __syncthreads();
    if (t < NBMAX && hist[t]) pos[t] = t * CAP + atomicAdd(&bucketCnt[t], hist[t]);
    __syncthreads();
#pragma unroll
    for (int k = 0; k < 8; k++)
        if (d[k] >= 0) {
            int p = atomicAdd(&pos[d[k] >> BSH], 1);
            pairs[p] = make_int2(s[k], d[k]);
        }
}

// ---------------- fat kernel 2 (512 thr, 64KB LDS): csr || gemm1 ----------------
// csr: 1 node/thread, padded scan -> rowInfo/dinv, LDS-cursor scatter -> col.
// gemm: 8 waves x 16 rows = 128 rows/block; W1f staged once (64KB); X preloaded
//       before the single staging barrier (forces register residency).
__global__ __launch_bounds__(512) void csr_gemm_kernel(
        const int2* __restrict__ pairs, const int* __restrict__ bucketCnt,
        int* __restrict__ rowInfo, float* __restrict__ dinv, int* __restrict__ col,
        const float* __restrict__ X, const unsigned short* __restrict__ W1f,
        unsigned char* __restrict__ H1, int N, int nbCsr) {
    __shared__ int sh[16384];   // 64KB
    int t = threadIdx.x;

    if (blockIdx.x < nbCsr) {
        // ---- CSR body: 512 threads, one node each ----
        int* cnt  = sh;          // [512]
        int* part = sh + 512;    // [512]
        int b = blockIdx.x;
        int n0 = b << BSH;
        int nn = N - n0; if (nn > 512) nn = 512;
        int in0 = b * CAP;
        int inEnd = in0 + bucketCnt[b];
        int out0 = b * PCAP;

        cnt[t] = 0;
        __syncthreads();
        for (int p = in0 + t; p < inEnd; p += 512)
            atomicAdd(&cnt[pairs[p].y - n0], 1);
        __syncthreads();

        int c0 = cnt[t];
        int p0 = (c0 + 15) & ~15;          // pad to 16
        part[t] = p0;
        __syncthreads();
        for (int off = 1; off < 512; off <<= 1) {
            int u = (t >= off) ? part[t - off] : 0;
            __syncthreads();
            part[t] += u;
            __syncthreads();
        }
        int e0 = out0 + part[t] - p0;      // padded exclusive start for node t
        __syncthreads();
        if (t < nn) {
            rowInfo[n0 + t] = ((e0 >> 4) << 12) | (p0 >> 4);
            dinv[n0 + t] = rsqrtf((float)(c0 + 1));
        }
        cnt[t] = e0;                        // cursor
        __syncthreads();

        for (int p = in0 + t; p < inEnd; p += 512) {
            int2 e = pairs[p];
            int q = atomicAdd(&cnt[e.y - n0], 1);
            col[q] = e.x;
        }
        __syncthreads();
        if (t < nn) for (int q = c0; q < p0; q++) col[e0 + q] = N;   // dummy pad
    } else {
        // ---- GEMM body: 8 waves x 16 rows = 128 rows/block ----
        int gb = blockIdx.x - nbCsr;
        int wm = t >> 6, l = t & 63;
        int lr = l & 15, lg = l >> 4;
        int bm = gb * 128 + wm * 16;

        int r = bm + lr;
        r = (r < N) ? r : (N - 1);
        const float* xp = X + (size_t)r * F_IN + lg * 8;

        // issue all 16 X loads BEFORE the staging barrier (barrier drains vmcnt ->
        // loads land under the W1f copy; compiler cannot sink them past it)
        float4 u[16];
#pragma unroll
        for (int s = 0; s < 8; s++) {
            u[2 * s + 0] = *(const float4*)(xp + s * 32);
            u[2 * s + 1] = *(const float4*)(xp + s * 32 + 4);
        }

        // stage entire repacked W1f (64KB) into LDS: 8 x uint4 per thread (512 thr)
        uint4* wv = (uint4*)sh;
        const uint4* wg = (const uint4*)W1f;
#pragma unroll
        for (int i = 0; i < 8; i++) wv[t + i * 512] = wg[t + i * 512];
        __syncthreads();
        const unsigned short* w1s = (const unsigned short*)sh;

        f32x4 acc[8];
#pragma unroll
        for (int f = 0; f < 8; f++) acc[f] = (f32x4){0.f, 0.f, 0.f, 0.f};

#pragma unroll
        for (int s = 0; s < 8; s++) {            // k-step of 32, X in regs, W1f in LDS
            float4 u0 = u[2 * s + 0];
            float4 u1 = u[2 * s + 1];
            bf16x8 a;
            a[0] = (short)f2bf(u0.x); a[1] = (short)f2bf(u0.y);
            a[2] = (short)f2bf(u0.z); a[3] = (short)f2bf(u0.w);
            a[4] = (short)f2bf(u1.x); a[5] = (short)f2bf(u1.y);
            a[6] = (short)f2bf(u1.z); a[7] = (short)f2bf(u1.w);
#pragma unroll
            for (int f = 0; f < 8; f++) {
                bf16x8 b = *(const bf16x8*)(w1s + ((((f * 32 + s * 4 + lg) * 16) + lr) << 3));
                acc[f] = __builtin_amdgcn_mfma_f32_16x16x32_bf16(a, b, acc[f], 0, 0, 0);
            }
        }
#pragma unroll
        for (int rr = 0; rr < 4; rr++) {
            int row = bm + lg * 4 + rr;
            if (row < N) {
                int w0 = __builtin_amdgcn_cvt_pk_fp8_f32(acc[0][rr], acc[1][rr], 0, false);
                w0 = __builtin_amdgcn_cvt_pk_fp8_f32(acc[2][rr], acc[3][rr], w0, true);
                int w1 = __builtin_amdgcn_cvt_pk_fp8_f32(acc[4][rr], acc[5][rr], 0, false);
                w1 = __builtin_amdgcn_cvt_pk_fp8_f32(acc[6][rr], acc[7][rr], w1, true);
                uint2 pk; pk.x = (unsigned)w0; pk.y = (unsigned)w1;
                *(uint2*)(H1 + ((size_t)row << 7) + lr * 8) = pk;
            }
        }
    }
}

// ---------------- agg1 fused: sum(dv_s * H1u[s]) -> *di + b1 -> relu -> @W2 -> *di -> H2(bf16) ----------------
__global__ __launch_bounds__(256, 8) void agg1_kernel(const unsigned char* __restrict__ H1,
                                                      const int* __restrict__ rowInfo,
                                                      const int* __restrict__ col,
                                                      const float* __restrict__ dinv,
                                                      const float* __restrict__ b1,
                                                      const float* __restrict__ W2,
                                                      unsigned short* __restrict__ H2, int N) {
    __shared__ f32x4 a_lds4[4][32];
    int tid = threadIdx.x;
    int wave = tid >> 6, lane = tid & 63;
    int d = blockIdx.x * 4 + wave;
    int half = lane >> 5;
    int li = lane & 31;
    unsigned kb4 = (unsigned)li * 4;

    float di = 0.f;
    if (d < N) {
        di = dinv[d];
        unsigned sg = *(const unsigned*)(H1 + (((unsigned)d << 7) | kb4));   // self row (unscaled)
        if (half) sg = 0u;
        f32x2 dsp = {di, di};
        f32x2 acc01 = __builtin_amdgcn_cvt_pk_f32_fp8((int)sg, false) * dsp;
        f32x2 acc23 = __builtin_amdgcn_cvt_pk_f32_fp8((int)sg, true) * dsp;

        int info = rowInfo[d];
        int jb = (info >> 12) << 4;
        int jend = jb + ((info & 0xFFF) << 4);
        for (int j0 = jb; j0 < jend; j0 += 64) {
            int cnt = jend - j0; if (cnt > 64) cnt = 64;   // multiple of 16
            int eidx = col[j0 + lane];
            if ((unsigned)eidx > (unsigned)N) eidx = N;    // clamp poison at bucket tails
            float dv = dinv[eidx];
            for (int kk = 0; kk < cnt; kk += 16) {         // 8 pair-gathers in flight
                int sA = __shfl(eidx, kk + 0 + half),  sB = __shfl(eidx, kk + 2 + half);
                int sC = __shfl(eidx, kk + 4 + half),  sD = __shfl(eidx, kk + 6 + half);
                int sE = __shfl(eidx, kk + 8 + half),  sF = __shfl(eidx, kk + 10 + half);
                int sG = __shfl(eidx, kk + 12 + half), sH = __shfl(eidx, kk + 14 + half);
                float vA = __shfl(dv, kk + 0 + half),  vB = __shfl(dv, kk + 2 + half);
                float vC = __shfl(dv, kk + 4 + half),  vD = __shfl(dv, kk + 6 + half);
                float vE = __shfl(dv, kk + 8 + half),  vF = __shfl(dv, kk + 10 + half);
                float vG = __shfl(dv, kk + 12 + half), vH = __shfl(dv, kk + 14 + half);
                unsigned gA = *(const unsigned*)(H1 + (((unsigned)sA << 7) | kb4));
                unsigned gB = *(const unsigned*)(H1 + (((unsigned)sB << 7) | kb4));
                unsigned gC = *(const unsigned*)(H1 + (((unsigned)sC << 7) | kb4));
                unsigned gD = *(const unsigned*)(H1 + (((unsigned)sD << 7) | kb4));
                unsigned gE = *(const unsigned*)(H1 + (((unsigned)sE << 7) | kb4));
                unsigned gF = *(const unsigned*)(H1 + (((unsigned)sF << 7) | kb4));
                unsigned gG = *(const unsigned*)(H1 + (((unsigned)sG << 7) | kb4));
                unsigned gH = *(const unsigned*)(H1 + (((unsigned)sH << 7) | kb4));
                f32x2 wA = {vA, vA}, wB = {vB, vB}, wC = {vC, vC}, wD = {vD, vD};
                f32x2 wE = {vE, vE}, wF = {vF, vF}, wG = {vG, vG}, wH = {vH, vH};
                acc01 += __builtin_amdgcn_cvt_pk_f32_fp8((int)gA, false) * wA;
                acc23 += __builtin_amdgcn_cvt_pk_f32_fp8((int)gA, true)  * wA;
                acc01 += __builtin_amdgcn_cvt_pk_f32_fp8((int)gB, false) * wB;
                acc23 += __builtin_amdgcn_cvt_pk_f32_fp8((int)gB, true)  * wB;
                acc01 += __builtin_amdgcn_cvt_pk_f32_fp8((int)gC, false) * wC;
                acc23 += __builtin_amdgcn_cvt_pk_f32_fp8((int)gC, true)  * wC;
                acc01 += __builtin_amdgcn_cvt_pk_f32_fp8((int)gD, false) * wD;
                acc23 += __builtin_amdgcn_cvt_pk_f32_fp8((int)gD, true)  * wD;
                acc01 += __builtin_amdgcn_cvt_pk_f32_fp8((int)gE, false) * wE;
                acc23 += __builtin_amdgcn_cvt_pk_f32_fp8((int)gE, true)  * wE;
                acc01 += __builtin_amdgcn_cvt_pk_f32_fp8((int)gF, false) * wF;
                acc23 += __builtin_amdgcn_cvt_pk_f32_fp8((int)gF, true)  * wF;
                acc01 += __builtin_amdgcn_cvt_pk_f32_fp8((int)gG, false) * wG;
                acc23 += __builtin_amdgcn_cvt_pk_f32_fp8((int)gG, true)  * wG;
                acc01 += __builtin_amdgcn_cvt_pk_f32_fp8((int)gH, false) * wH;
                acc23 += __builtin_amdgcn_cvt_pk_f32_fp8((int)gH, true)  * wH;
            }
        }
        acc01.x += __shfl_xor(acc01.x, 32);
        acc01.y += __shfl_xor(acc01.y, 32);
        acc23.x += __shfl_xor(acc23.x, 32);
        acc23.y += __shfl_xor(acc23.y, 32);
        if (half == 0) {
            int p0 = li * 4;
            int f0 = ((p0 & 7) << 4) | (p0 >> 3);
            int f1 = (((p0 + 1) & 7) << 4) | ((p0 + 1) >> 3);
            int f2 = (((p0 + 2) & 7) << 4) | ((p0 + 2) >> 3);
            int f3 = (((p0 + 3) & 7) << 4) | ((p0 + 3) >> 3);
            f32x4 a;
            a[0] = fmaxf(fmaf(acc01.x, di, b1[f0]), 0.f);
            a[1] = fmaxf(fmaf(acc01.y, di, b1[f1]), 0.f);
            a[2] = fmaxf(fmaf(acc23.x, di, b1[f2]), 0.f);
            a[3] = fmaxf(fmaf(acc23.y, di, b1[f3]), 0.f);
            a_lds4[wave][li] = a;
        }
    }
    __syncthreads();
    if (d < N) {
        int c = lane & 15, kg = lane >> 4;
        const float* a_ldsf = (const float*)a_lds4[wave];
        const float* w2b = W2 + kg * 64 + c;
        float p = 0.f;
#pragma unroll
        for (int i = 0; i < 32; i++) {
            int w2off = ((i & 7) << 8) + ((i >> 3) << 4);
            p = fmaf(a_ldsf[kg * 32 + i], w2b[w2off], p);
        }
        p += __shfl_xor(p, 16);
        p += __shfl_xor(p, 32);
        if (lane < 16) H2[(size_t)d * NCLS + c] = f2bf(p * di);
    }
}

// ---------------- agg2 + log_softmax: 8 lanes/node, 2 classes/lane, 16-padded lists ----------------
__global__ __launch_bounds__(256, 8) void agg2_kernel(const unsigned short* __restrict__ H2,
                                                      const int* __restrict__ rowInfo,
                                                      const int* __restrict__ col,
                                                      const float* __restrict__ dinv,
                                                      const float* __restrict__ b2,
                                                      float* __restrict__ OUT, int N) {
    int tid = threadIdx.x;
    int g = tid >> 3, q = tid & 7;
    int d = blockIdx.x * 32 + g;
    if (d >= N) return;
    unsigned cb = (unsigned)q * 4;
    const char* H2b = (const char*)H2;
    float di = dinv[d];
    unsigned u = *(const unsigned*)(H2b + (((unsigned)d << 5) | cb));
    f32x2 acc; acc.x = bflo(u); acc.y = bfhi(u);
    int info = rowInfo[d];
    int jb = (info >> 12) << 4;
    int jend = jb + ((info & 0xFFF) << 4);
    for (int j = jb; j < jend; j += 8) {
        unsigned u0 = *(const unsigned*)(H2b + (((unsigned)col[j + 0] << 5) | cb));
        unsigned u1 = *(const unsigned*)(H2b + (((unsigned)col[j + 1] << 5) | cb));
        unsigned u2 = *(const unsigned*)(H2b + (((unsigned)col[j + 2] << 5) | cb));
        unsigned u3 = *(const unsigned*)(H2b + (((unsigned)col[j + 3] << 5) | cb));
        unsigned u4 = *(const unsigned*)(H2b + (((unsigned)col[j + 4] << 5) | cb));
        unsigned u5 = *(const unsigned*)(H2b + (((unsigned)col[j + 5] << 5) | cb));
        unsigned u6 = *(const unsigned*)(H2b + (((unsigned)col[j + 6] << 5) | cb));
        unsigned u7 = *(const unsigned*)(H2b + (((unsigned)col[j + 7] << 5) | cb));
        f32x2 v0; v0.x = bflo(u0); v0.y = bfhi(u0);
        f32x2 v1; v1.x = bflo(u1); v1.y = bfhi(u1);
        f32x2 v2; v2.x = bflo(u2); v2.y = bfhi(u2);
        f32x2 v3; v3.x = bflo(u3); v3.y = bfhi(u3);
        f32x2 v4; v4.x = bflo(u4); v4.y = bfhi(u4);
        f32x2 v5; v5.x = bflo(u5); v5.y = bfhi(u5);
        f32x2 v6; v6.x = bflo(u6); v6.y = bfhi(u6);
        f32x2 v7; v7.x = bflo(u7); v7.y = bfhi(u7);
        acc += ((v0 + v1) + (v2 + v3)) + ((v4 + v5) + (v6 + v7));
    }
    float l0 = fmaf(acc.x, di, b2[q * 2]);
    float l1 = fmaf(acc.y, di, b2[q * 2 + 1]);
    float m = fmaxf(l0, l1);
    m = fmaxf(m, __shfl_xor(m, 1, 8));
    m = fmaxf(m, __shfl_xor(m, 2, 8));
    m = fmaxf(m, __shfl_xor(m, 4, 8));
    float e = __expf(l0 - m) + __expf(l1 - m);
    e += __shfl_xor(e, 1, 8);
    e += __shfl_xor(e, 2, 8);
    e += __shfl_xor(e, 4, 8);
    float ls = __logf(e);
    float2 o; o.x = l0 - m - ls; o.y = l1 - m - ls;
    *(float2*)(OUT + ((size_t)d << 4) + q * 2) = o;
}

// ---------------- launch ----------------
extern "C" void kernel_launch(void* const* d_in, const int* in_sizes, int n_in,
                              void* d_out, int out_size, void* d_ws, size_t ws_size,
                              hipStream_t stream) {
    const float* x  = (const float*)d_in[0];
    const int*   ei = (const int*)d_in[1];
    const float* W1 = (const float*)d_in[2];
    const float* b1 = (const float*)d_in[3];
    const float* W2 = (const float*)d_in[4];
    const float* b2 = (const float*)d_in[5];
    float* out = (float*)d_out;

    const int N = in_sizes[0] / F_IN;    // 100000
    const int E = in_sizes[1] / 2;       // 1600000
    const int* src = ei;
    const int* dst = ei + E;
    const int nb = (N + (1 << BSH) - 1) >> BSH;   // 196 buckets

    // workspace layout (256B aligned)
    char* ws = (char*)d_ws;
    size_t off = 0;
    auto alloc = [&](size_t bytes) {
        size_t o = off;
        off += (bytes + 255) & ~(size_t)255;
        return (void*)(ws + o);
    };
    int*            bucketCnt   = (int*)alloc(NBMAX * 4);
    int*            rowInfo     = (int*)alloc((size_t)N * 4);
    float*          dinv        = (float*)alloc((size_t)(N + 1) * 4);
    int*            colw        = (int*)alloc((size_t)NBMAX * PCAP * 4);
    unsigned short* w1f         = (unsigned short*)alloc(32768 * 2);
    unsigned short* h2          = (unsigned short*)alloc((size_t)(N + 1) * NCLS * 2);
    // pairs and h1 must NOT overlap (csr reads pairs while gemm writes h1 in same kernel)
    int2*           pairs       = (int2*)alloc((size_t)NBMAX * CAP * 8);
    unsigned char*  h1          = (unsigned char*)alloc((size_t)(N + 1) * DIM);
    (void)ws_size;

    const int gridE = (E + 8191) / 8192;   // 196 part blocks
    const int initB = 32;                  // 32768 repack elems / 1024

    hipMemsetAsync(bucketCnt, 0, NBMAX * 4, stream);
    part_init_kernel<<<gridE + initB, 1024, 0, stream>>>(src, dst, bucketCnt, pairs, E,
                                                         W1, w1f,
                                                         (unsigned*)(h1 + (size_t)N * DIM),
                                                         (unsigned*)(h2 + (size_t)N * NCLS),
                                                         dinv, N, gridE);
    csr_gemm_kernel<<<nb + (N + 127) / 128, 512, 0, stream>>>(pairs, bucketCnt, rowInfo, dinv, colw,
                                                              x, w1f, h1, N, nb);
    agg1_kernel<<<(N + 3) / 4, 256, 0, stream>>>(h1, rowInfo, colw, dinv, b1, W2, h2, N);
    agg2_kernel<<<(N + 31) / 32, 256, 0, stream>>>(h2, rowInfo, colw, dinv, b2, out, N);
}